// Round 10
// baseline (232.642 us; speedup 1.0000x reference)
//
#include <hip/hip_runtime.h>

typedef __attribute__((ext_vector_type(8))) short bf16x8;
typedef __attribute__((ext_vector_type(4))) float f32x4;

#define LOG2E 1.4426950408889634f

static __device__ __forceinline__ unsigned short f2bf(float f) {
    unsigned int u = __builtin_bit_cast(unsigned int, f);
    u += 0x7fffu + ((u >> 16) & 1u);   // round-to-nearest-even
    return (unsigned short)(u >> 16);
}
// raw v_exp_f32: skips OCML's denormal-range fixup (S is bounded, |S|<~30)
static __device__ __forceinline__ float exp2_raw(float x) {
    float r;
    asm("v_exp_f32 %0, %1" : "=v"(r) : "v"(x));
    return r;
}
// async global->LDS, 16B per lane; LDS dest = wave-uniform base + lane*16
static __device__ __forceinline__ void gload_lds16(const void* g, void* l) {
    __builtin_amdgcn_global_load_lds(
        (const __attribute__((address_space(1))) void*)g,
        (__attribute__((address_space(3))) void*)l, 16, 0, 0);
}

// ---------------- preprocessing: convert x (blocks 0..2047),
// ---------------- transpose+convert 4 weights (blocks 2048..6143)
__launch_bounds__(256)
__global__ void prep(const float* __restrict__ x,
                     unsigned short* __restrict__ xb,
                     const float* __restrict__ W0, const float* __restrict__ W1,
                     const float* __restrict__ W2, const float* __restrict__ W3,
                     unsigned short* __restrict__ T0, unsigned short* __restrict__ T1,
                     unsigned short* __restrict__ T2, unsigned short* __restrict__ T3) {
    int id = blockIdx.x, tid = threadIdx.x;

    if (id < 2048) {                              // ---- x fp32 -> bf16
        int i = id * 256 + tid;
        const float4* s4 = (const float4*)x;
        float4 a = s4[2 * i], b = s4[2 * i + 1];
        uint4 u;
        u.x = (unsigned)f2bf(a.x) | ((unsigned)f2bf(a.y) << 16);
        u.y = (unsigned)f2bf(a.z) | ((unsigned)f2bf(a.w) << 16);
        u.z = (unsigned)f2bf(b.x) | ((unsigned)f2bf(b.y) << 16);
        u.w = (unsigned)f2bf(b.z) | ((unsigned)f2bf(b.w) << 16);
        *(uint4*)(xb + 8 * (size_t)i) = u;
        return;
    }
    {                                             // ---- weight transpose+cvt
        __shared__ float t[32][33];
        int j = id - 2048, which = j >> 10, r = j & 1023;
        const float* W = (which == 0) ? W0 : (which == 1) ? W1
                         : (which == 2) ? W2 : W3;
        unsigned short* Wt = (which == 0) ? T0 : (which == 1) ? T1
                             : (which == 2) ? T2 : T3;
        int tx = tid & 31, ty = tid >> 5;          // 32 x 8
        int x0 = (r & 31) * 32, y0 = (r >> 5) * 32;
        for (int i = 0; i < 4; i++)
            t[ty + 8 * i][tx] = W[(size_t)(y0 + ty + 8 * i) * 1024 + x0 + tx];
        __syncthreads();
        for (int i = 0; i < 4; i++)
            Wt[(size_t)(x0 + ty + 8 * i) * 1024 + y0 + tx] =
                f2bf(t[tx][ty + 8 * i]);
    }
}

// ------------------------------------------------------------ QKV GEMM
// blockIdx.y < 24: GEMM blocks (which = y>>3, n-tile = y&7).
// blockIdx.y >= 24: bias-permute blocks (memory-bound, no dependency on
// the GEMM inputs) -- overlap with the compute-bound GEMM blocks.
// Bias fragment order = S^T layout (attn computes mfma(K,Q)):
//   elem (c,r) for lane (quad,l16):  q = e*64+w*16+l16, k = c*16+quad*4+r
//   -> r-inner = 4 consecutive u16 = one uint2 LDS read.
__launch_bounds__(256)
__global__ void gemm_qkv(const unsigned short* __restrict__ A,
                         const unsigned short* __restrict__ WqT,
                         const unsigned short* __restrict__ WkT,
                         const unsigned short* __restrict__ WvT,
                         const float* __restrict__ bq,
                         const float* __restrict__ bk,
                         const float* __restrict__ bv,
                         const float* __restrict__ alpha,
                         const float* __restrict__ bias2d,
                         unsigned short* __restrict__ biasP,
                         unsigned short* __restrict__ Qb,
                         unsigned short* __restrict__ Kb,
                         unsigned short* __restrict__ Vtb) {
    __shared__ __align__(16) unsigned short sh[16384];   // 32 KB union
    int tid = threadIdx.x;

    if (blockIdx.y >= 24) {            // ---------------- bias permute
        int id = blockIdx.x + 32 * (blockIdx.y - 24);    // 0..1023
        int mt = id & 31, qt = (id >> 5) & 15, b = id >> 9;
        const float* s = bias2d + (size_t)b * 2048 * 2048;
        // stage 128x64 tile as bf16*LOG2E into sh[row*68+col] (coalesced)
        for (int p = 0; p < 8; p++) {
            int row = p * 16 + (tid >> 4), f4 = tid & 15;
            float4 v = *(const float4*)
                &s[(size_t)(qt * 128 + row) * 2048 + mt * 64 + f4 * 4];
            uint2 u;
            u.x = (unsigned)f2bf(v.x * LOG2E) | ((unsigned)f2bf(v.y * LOG2E) << 16);
            u.y = (unsigned)f2bf(v.z * LOG2E) | ((unsigned)f2bf(v.w * LOG2E) << 16);
            *(uint2*)&sh[row * 68 + f4 * 4] = u;
        }
        __syncthreads();
        int w = tid >> 6, lane = tid & 63, quad = lane >> 4, l16 = lane & 15;
        unsigned short* d = biasP + (((size_t)(b * 16 + qt) * 32 + mt) * 8192);
        for (int e = 0; e < 2; e++) {
            unsigned short vals[16];
            for (int c = 0; c < 4; c++)
                *(uint2*)&vals[c * 4] = *(const uint2*)
                    &sh[(e * 64 + w * 16 + l16) * 68 + c * 16 + quad * 4];
            unsigned short* o = d + ((size_t)((e * 4 + w) * 64 + lane)) * 16;
            *(bf16x8*)&o[0] = *(bf16x8*)&vals[0];
            *(bf16x8*)&o[8] = *(bf16x8*)&vals[8];
        }
        return;
    }

    // ---------------- GEMM part
    unsigned short (*As)[64] = (unsigned short(*)[64])sh;          // [128][64]
    unsigned short (*Bs)[64] = (unsigned short(*)[64])(sh + 8192); // [128][64]
    int which = blockIdx.y >> 3;
    const unsigned short* Bt = (which == 0) ? WqT : (which == 1) ? WkT : WvT;
    const float* bias = (which == 0) ? bq : (which == 1) ? bk : bv;

    int wave = tid >> 6, lane = tid & 63, quad = lane >> 4, l16 = lane & 15;
    int wm = wave & 1, wn = wave >> 1;
    int lrow = lane >> 3, lblk = lane & 7;
    int swz = ((lblk ^ lrow) * 8);
    int m0 = blockIdx.x * 128, n0 = (blockIdx.y & 7) * 128;
    f32x4 acc[4][4] = {};

    for (int kt = 0; kt < 16; kt++) {
        int k0 = kt * 64;
        for (int i = 0; i < 4; i++) {
            int rbase = i * 32 + wave * 8;
            gload_lds16(&A[(size_t)(m0 + rbase + lrow) * 1024 + k0 + swz],
                        &As[rbase][0]);
            gload_lds16(&Bt[(size_t)(n0 + rbase + lrow) * 1024 + k0 + swz],
                        &Bs[rbase][0]);
        }
        __syncthreads();
        for (int ks = 0; ks < 2; ks++) {
            int pblk = ((ks * 4 + quad) ^ (l16 & 7)) * 8;
            bf16x8 af[4], bf_[4];
            for (int i = 0; i < 4; i++)
                af[i] = *(const bf16x8*)&As[64 * wm + 16 * i + l16][pblk];
            for (int j = 0; j < 4; j++)
                bf_[j] = *(const bf16x8*)&Bs[64 * wn + 16 * j + l16][pblk];
            if (which == 2) {
                for (int i = 0; i < 4; i++)
                    for (int j = 0; j < 4; j++)
                        acc[i][j] = __builtin_amdgcn_mfma_f32_16x16x32_bf16(
                            af[i], bf_[j], acc[i][j], 0, 0, 0);
            } else {   // swapped: acc[i][j] = C^T block (row=weight col, col=token)
                for (int i = 0; i < 4; i++)
                    for (int j = 0; j < 4; j++)
                        acc[i][j] = __builtin_amdgcn_mfma_f32_16x16x32_bf16(
                            bf_[j], af[i], acc[i][j], 0, 0, 0);
            }
        }
        __syncthreads();
    }

    if (which == 2) {
        for (int i = 0; i < 4; i++)
            for (int j = 0; j < 4; j++) {
                int colb = n0 + 64 * wn + 16 * j + l16;
                int h = colb >> 6, dk = colb & 63;
                int row0 = m0 + 64 * wm + 16 * i + quad * 4;
                int bb = row0 >> 11, nn0 = row0 & 2047;
                unsigned short v4[4];
                for (int r = 0; r < 4; r++) {
                    float v = acc[i][j][r] + bias[colb];
                    v4[r] = f2bf(v * (1.0f + alpha[bb * 2048 + nn0 + r]));
                }
                uint2 u;
                u.x = (unsigned)v4[0] | ((unsigned)v4[1] << 16);
                u.y = (unsigned)v4[2] | ((unsigned)v4[3] << 16);
                *(uint2*)&Vtb[((size_t)(bb * 16 + h) * 64 + dk) * 2048 + nn0] = u;
            }
    } else {
        unsigned short* outb = (which == 0) ? Qb : Kb;
        for (int i = 0; i < 4; i++)
            for (int j = 0; j < 4; j++) {
                int row = m0 + 64 * wm + 16 * i + l16;          // token
                int bb = row >> 11, nn = row & 2047;
                int colb0 = n0 + 64 * wn + 16 * j + quad * 4;   // 4 consec cols
                int h = colb0 >> 6, dk0 = colb0 & 63;
                float4 b4 = *(const float4*)&bias[colb0];
                float s = (which == 0) ? (0.125f * LOG2E)
                                       : (1.0f + alpha[bb * 2048 + nn]);
                unsigned short v4[4];
                v4[0] = f2bf((acc[i][j][0] + b4.x) * s);
                v4[1] = f2bf((acc[i][j][1] + b4.y) * s);
                v4[2] = f2bf((acc[i][j][2] + b4.z) * s);
                v4[3] = f2bf((acc[i][j][3] + b4.w) * s);
                uint2 u;
                u.x = (unsigned)v4[0] | ((unsigned)v4[1] << 16);
                u.y = (unsigned)v4[2] | ((unsigned)v4[3] << 16);
                *(uint2*)&outb[((size_t)(bb * 16 + h) * 2048 + nn) * 64 + dk0] = u;
            }
    }
}

// ------------------------------------------------ out projection GEMM (fp32)
// 128x64 tiles -> grid (32,16) = 512 blocks = 2 blocks/CU.
__launch_bounds__(256)
__global__ void gemm_out(const unsigned short* __restrict__ A,
                         const unsigned short* __restrict__ Bt,
                         const float* __restrict__ bias,
                         float* __restrict__ outf) {
    __shared__ __align__(16) unsigned short As[128][64];   // 16 KB
    __shared__ __align__(16) unsigned short Bs[64][64];    //  8 KB
    int tid = threadIdx.x;
    int wave = tid >> 6, lane = tid & 63, quad = lane >> 4, l16 = lane & 15;
    int wm = wave & 1, wn = wave >> 1;        // wn in 0..1
    int lrow = lane >> 3, lblk = lane & 7;
    int swz = ((lblk ^ lrow) * 8);
    int m0 = blockIdx.x * 128, n0 = blockIdx.y * 64;
    f32x4 acc[4][2] = {};

    for (int kt = 0; kt < 16; kt++) {
        int k0 = kt * 64;
        for (int i = 0; i < 4; i++) {
            int rbase = i * 32 + wave * 8;
            gload_lds16(&A[(size_t)(m0 + rbase + lrow) * 1024 + k0 + swz],
                        &As[rbase][0]);
        }
        for (int i = 0; i < 2; i++) {
            int rbase = i * 32 + wave * 8;
            gload_lds16(&Bt[(size_t)(n0 + rbase + lrow) * 1024 + k0 + swz],
                        &Bs[rbase][0]);
        }
        __syncthreads();
        for (int ks = 0; ks < 2; ks++) {
            int pblk = ((ks * 4 + quad) ^ (l16 & 7)) * 8;
            bf16x8 af[4], bf_[2];
            for (int i = 0; i < 4; i++)
                af[i] = *(const bf16x8*)&As[64 * wm + 16 * i + l16][pblk];
            for (int j = 0; j < 2; j++)
                bf_[j] = *(const bf16x8*)&Bs[32 * wn + 16 * j + l16][pblk];
            for (int i = 0; i < 4; i++)
                for (int j = 0; j < 2; j++)
                    acc[i][j] = __builtin_amdgcn_mfma_f32_16x16x32_bf16(
                        bf_[j], af[i], acc[i][j], 0, 0, 0);
        }
        __syncthreads();
    }

    for (int i = 0; i < 4; i++)
        for (int j = 0; j < 2; j++) {
            int row = m0 + 64 * wm + 16 * i + l16;          // token
            int colb0 = n0 + 32 * wn + 16 * j + quad * 4;   // 4 consec cols
            float4 b4 = *(const float4*)&bias[colb0];
            float4 o;
            o.x = acc[i][j][0] + b4.x;
            o.y = acc[i][j][1] + b4.y;
            o.z = acc[i][j][2] + b4.z;
            o.w = acc[i][j][3] + b4.w;
            *(float4*)&outf[(size_t)row * 1024 + colb0] = o;
        }
}

// ----------------------------------------------------- flash attention
// Round-9 structure + S^T QK (mfma(K,Q)): lane holds 4 CONSECUTIVE k per
// fragment -> P stores become 8 packed ds_write_b64/tile (was 32 scalar
// b16), targeting the LDS pipe (~70% occupied per DS-op arithmetic).
// The P READ path (swizzled b128, blkr rotation) is kept bit-identical:
// write block pb = (c*2+(quad>>1) + (l16>>2))&7 is the exact inverse of
// read blkr = (ks*4+quad + (l16>>2))&7 with elem j = k%8 = (quad&1)*4+r.
__launch_bounds__(256, 4)
__global__ void attn_kernel(const unsigned short* __restrict__ Q,
                            const unsigned short* __restrict__ K,
                            const unsigned short* __restrict__ Vt,
                            const unsigned short* __restrict__ biasP,
                            unsigned short* __restrict__ Y,
                            float* __restrict__ Opart,
                            float* __restrict__ Lpart, int split) {
    __shared__ __align__(16) unsigned short Ks[64][64];
    __shared__ __align__(16) unsigned short Vs[64][64];
    __shared__ __align__(16) unsigned short Ps[4][32][72];
    int tid = threadIdx.x;
    int wave = tid >> 6, lane = tid & 63, quad = lane >> 4, l16 = lane & 15;
    int qt = blockIdx.x, h = blockIdx.y;
    int b, mt0, mtN;
    if (split) { b = blockIdx.z >> 1; int half = blockIdx.z & 1;
                 mt0 = half * 16; mtN = mt0 + 16; }
    else       { b = blockIdx.z; mt0 = 0; mtN = 32; }
    int q0 = qt * 128;
    size_t headoff = (size_t)(b * 16 + h) * 2048 * 64;
    const unsigned short* Kp = K + headoff;
    const unsigned short* Vp = Vt + headoff;
    int lrow = lane >> 3, lblk = lane & 7;
    int swz = (lblk ^ lrow) * 8;

    bf16x8 aq[2][2];
    for (int e = 0; e < 2; e++) {
        const unsigned short* qp =
            Q + headoff + (size_t)(q0 + e * 64 + wave * 16 + l16) * 64;
        aq[e][0] = *(const bf16x8*)&qp[quad * 8];
        aq[e][1] = *(const bf16x8*)&qp[32 + quad * 8];
    }
    bf16x8 ones;
    for (int j = 0; j < 8; j++) ones[j] = (short)0x3F80;   // bf16 1.0

    f32x4 oacc[2][4] = {};
    f32x4 lacc[2] = {};
    const unsigned short* bP = biasP + (size_t)(b * 16 + qt) * 32 * 8192;

    for (int mt = mt0; mt < mtN; mt++) {
        int m0 = mt * 64;
        for (int i = 0; i < 2; i++) {
            int rbase = wave * 16 + i * 8;
            gload_lds16(&Kp[(size_t)(m0 + rbase + lrow) * 64 + swz], &Ks[rbase][0]);
            gload_lds16(&Vp[(size_t)(rbase + lrow) * 2048 + m0 + swz], &Vs[rbase][0]);
        }
        const unsigned short* bt = bP + (size_t)mt * 8192;
        bf16x8 bz[2][2];
        for (int e = 0; e < 2; e++) {
            const unsigned short* p = bt + (size_t)((e * 4 + wave) * 64 + lane) * 16;
            bz[e][0] = *(const bf16x8*)&p[0];
            bz[e][1] = *(const bf16x8*)&p[8];
        }
        __syncthreads();

        // S^T = bias^T + (Q K^T)^T : operands swapped so lane (quad,l16)
        // holds q = l16, k = c*16 + quad*4 + r  (4 consecutive k).
        f32x4 sc[2][4];
        for (int e = 0; e < 2; e++)
            for (int c = 0; c < 4; c++) {
                uint2 w = ((const uint2*)&bz[e][c >> 1])[c & 1];
                f32x4 s;
                s[0] = __builtin_bit_cast(float, w.x << 16);
                s[1] = __builtin_bit_cast(float, w.x & 0xffff0000u);
                s[2] = __builtin_bit_cast(float, w.y << 16);
                s[3] = __builtin_bit_cast(float, w.y & 0xffff0000u);
                sc[e][c] = s;
            }
        __builtin_amdgcn_s_setprio(1);
        for (int c = 0; c < 4; c++) {
            for (int ks = 0; ks < 2; ks++) {
                bf16x8 kf = *(const bf16x8*)&Ks[c * 16 + l16]
                                               [((ks * 4 + quad) ^ (l16 & 7)) * 8];
                sc[0][c] = __builtin_amdgcn_mfma_f32_16x16x32_bf16(kf, aq[0][ks], sc[0][c], 0, 0, 0);
                sc[1][c] = __builtin_amdgcn_mfma_f32_16x16x32_bf16(kf, aq[1][ks], sc[1][c], 0, 0, 0);
            }
        }
        __builtin_amdgcn_s_setprio(0);

        // P = exp2(S) -> Ps, packed 8B stores (truncated bf16).
        // Row = e*16 + l16 (q), block pb matches the read-side rotation.
        for (int e = 0; e < 2; e++)
            for (int c = 0; c < 4; c++) {
                unsigned int b0 = __builtin_bit_cast(unsigned int, exp2_raw(sc[e][c][0]));
                unsigned int b1 = __builtin_bit_cast(unsigned int, exp2_raw(sc[e][c][1]));
                unsigned int b2 = __builtin_bit_cast(unsigned int, exp2_raw(sc[e][c][2]));
                unsigned int b3 = __builtin_bit_cast(unsigned int, exp2_raw(sc[e][c][3]));
                uint2 u;
                u.x = (b0 >> 16) | (b1 & 0xffff0000u);
                u.y = (b2 >> 16) | (b3 & 0xffff0000u);
                int pb = ((c * 2 + (quad >> 1)) + (l16 >> 2)) & 7;
                *(uint2*)&Ps[wave][e * 16 + l16][pb * 8 + (quad & 1) * 4] = u;
            }

        // O += P V ; l += P 1   (read path identical to round 9)
        __builtin_amdgcn_s_setprio(1);
        for (int ks = 0; ks < 2; ks++) {
            int blkr = (ks * 4 + quad + (l16 >> 2)) & 7;
            bf16x8 pf0 = *(const bf16x8*)&Ps[wave][l16][blkr * 8];
            bf16x8 pf1 = *(const bf16x8*)&Ps[wave][16 + l16][blkr * 8];
            lacc[0] = __builtin_amdgcn_mfma_f32_16x16x32_bf16(pf0, ones, lacc[0], 0, 0, 0);
            lacc[1] = __builtin_amdgcn_mfma_f32_16x16x32_bf16(pf1, ones, lacc[1], 0, 0, 0);
            for (int cv = 0; cv < 4; cv++) {
                bf16x8 vf = *(const bf16x8*)&Vs[cv * 16 + l16]
                                               [((ks * 4 + quad) ^ (l16 & 7)) * 8];
                oacc[0][cv] = __builtin_amdgcn_mfma_f32_16x16x32_bf16(pf0, vf, oacc[0][cv], 0, 0, 0);
                oacc[1][cv] = __builtin_amdgcn_mfma_f32_16x16x32_bf16(pf1, vf, oacc[1][cv], 0, 0, 0);
            }
        }
        __builtin_amdgcn_s_setprio(0);
        __syncthreads();
    }

    if (split) {
        size_t p = ((size_t)((b * 16 + h) * 16 + qt)) * 2 + (blockIdx.z & 1);
        float* Op = Opart + p * 8192;
        for (int e = 0; e < 2; e++)
            for (int cv = 0; cv < 4; cv++)
                for (int r = 0; r < 4; r++)
                    Op[(e * 64 + wave * 16 + quad * 4 + r) * 64 + cv * 16 + l16] =
                        oacc[e][cv][r];
        if (l16 == 0)
            for (int e = 0; e < 2; e++)
                for (int r = 0; r < 4; r++)
                    Lpart[p * 128 + e * 64 + wave * 16 + quad * 4 + r] = lacc[e][r];
    } else {
        for (int e = 0; e < 2; e++) {
            float invl[4];
            for (int r = 0; r < 4; r++) invl[r] = 1.0f / lacc[e][r];
            for (int cv = 0; cv < 4; cv++)
                for (int r = 0; r < 4; r++) {
                    int qrow = q0 + e * 64 + 16 * wave + quad * 4 + r;
                    int d = h * 64 + cv * 16 + l16;
                    Y[((size_t)b * 2048 + qrow) * 1024 + d] =
                        f2bf(oacc[e][cv][r] * invl[r]);
                }
        }
    }
}

// -------------------------------------------- combine split-K partials -> Y
__global__ void attn_combine(const float* __restrict__ Opart,
                             const float* __restrict__ Lpart,
                             unsigned short* __restrict__ Y) {
    int blk = blockIdx.x;                    // (b*16+h)*16+qt, 512 blocks
    int qt = blk & 15, h = (blk >> 4) & 15, b = blk >> 8;
    const float* O0 = Opart + (size_t)blk * 2 * 8192;
    const float* O1 = O0 + 8192;
    const float* L0 = Lpart + (size_t)blk * 2 * 128;
    const float* L1 = L0 + 128;
    int t = threadIdx.x;
    for (int i = 0; i < 8; i++) {
        int idx4 = i * 256 + t;              // float4 index (2048 total)
        int q = idx4 >> 4;
        int dk = (idx4 & 15) * 4;
        float4 a = *(const float4*)&O0[idx4 * 4];
        float4 c = *(const float4*)&O1[idx4 * 4];
        float inv = 1.0f / (L0[q] + L1[q]);
        uint2 u;
        u.x = (unsigned)f2bf((a.x + c.x) * inv) |
              ((unsigned)f2bf((a.y + c.y) * inv) << 16);
        u.y = (unsigned)f2bf((a.z + c.z) * inv) |
              ((unsigned)f2bf((a.w + c.w) * inv) << 16);
        int qrow = qt * 128 + q;
        *(uint2*)&Y[((size_t)b * 2048 + qrow) * 1024 + h * 64 + dk] = u;
    }
}

// ---------------------------------------------------------------- launcher
extern "C" void kernel_launch(void* const* d_in, const int* in_sizes, int n_in,
                              void* d_out, int out_size, void* d_ws, size_t ws_size,
                              hipStream_t stream) {
    const float* x     = (const float*)d_in[0];
    const float* alpha = (const float*)d_in[1];
    const float* bias  = (const float*)d_in[2];
    const float* Wq    = (const float*)d_in[3];
    const float* bq    = (const float*)d_in[4];
    const float* Wk    = (const float*)d_in[5];
    const float* bk    = (const float*)d_in[6];
    const float* Wv    = (const float*)d_in[7];
    const float* bv    = (const float*)d_in[8];
    const float* Wo    = (const float*)d_in[9];
    const float* bo    = (const float*)d_in[10];
    float* out = (float*)d_out;

    char* ws = (char*)d_ws;
    const size_t MB = 1048576;
    unsigned short* xb    = (unsigned short*)(ws);            // [0,8M), Yb later
    unsigned short* wqt   = (unsigned short*)(ws + 8 * MB);
    unsigned short* wkt   = (unsigned short*)(ws + 10 * MB);
    unsigned short* wvt   = (unsigned short*)(ws + 12 * MB);
    unsigned short* wot   = (unsigned short*)(ws + 14 * MB);
    unsigned short* Qb    = (unsigned short*)(ws + 16 * MB);
    unsigned short* Kb    = (unsigned short*)(ws + 24 * MB);
    unsigned short* Vtb   = (unsigned short*)(ws + 32 * MB);
    unsigned short* biasP = (unsigned short*)(ws + 40 * MB);  // 16 MB
    float*          Opart = (float*)(ws + 56 * MB);           // 32 MB
    float*          Lpart = (float*)(ws + 88 * MB);           // 0.5 MB
    unsigned short* Yb    = xb;
    int split = (ws_size >= 90 * MB) ? 1 : 0;

    prep<<<6144, 256, 0, stream>>>(x, xb, Wq, Wk, Wv, Wo, wqt, wkt, wvt, wot);

    // GEMM blocks (y<24) + bias-permute blocks (y>=24, overlapped)
    gemm_qkv<<<dim3(32, 56), 256, 0, stream>>>(
        xb, wqt, wkt, wvt, bq, bk, bv, alpha, bias, biasP, Qb, Kb, Vtb);

    if (split) {
        attn_kernel<<<dim3(16, 16, 4), 256, 0, stream>>>(
            Qb, Kb, Vtb, biasP, Yb, Opart, Lpart, 1);
        attn_combine<<<512, 256, 0, stream>>>(Opart, Lpart, Yb);
    } else {
        attn_kernel<<<dim3(16, 16, 2), 256, 0, stream>>>(
            Qb, Kb, Vtb, biasP, Yb, Opart, Lpart, 0);
    }

    gemm_out<<<dim3(32, 16), 256, 0, stream>>>(Yb, wot, bo, out);
}

// Round 11
// 227.418 us; speedup vs baseline: 1.0230x; 1.0230x over previous
//
#include <hip/hip_runtime.h>

typedef __attribute__((ext_vector_type(8))) short bf16x8;
typedef __attribute__((ext_vector_type(4))) float f32x4;

#define LOG2E 1.4426950408889634f

static __device__ __forceinline__ unsigned short f2bf(float f) {
    unsigned int u = __builtin_bit_cast(unsigned int, f);
    u += 0x7fffu + ((u >> 16) & 1u);   // round-to-nearest-even
    return (unsigned short)(u >> 16);
}
// raw v_exp_f32: skips OCML's denormal-range fixup (S is bounded, |S|<~30)
static __device__ __forceinline__ float exp2_raw(float x) {
    float r;
    asm("v_exp_f32 %0, %1" : "=v"(r) : "v"(x));
    return r;
}
// async global->LDS, 16B per lane; LDS dest = wave-uniform base + lane*16
static __device__ __forceinline__ void gload_lds16(const void* g, void* l) {
    __builtin_amdgcn_global_load_lds(
        (const __attribute__((address_space(1))) void*)g,
        (__attribute__((address_space(3))) void*)l, 16, 0, 0);
}

// ---------------- preprocessing: convert x (blocks 0..2047),
// ---------------- transpose+convert 4 weights (blocks 2048..6143)
__launch_bounds__(256)
__global__ void prep(const float* __restrict__ x,
                     unsigned short* __restrict__ xb,
                     const float* __restrict__ W0, const float* __restrict__ W1,
                     const float* __restrict__ W2, const float* __restrict__ W3,
                     unsigned short* __restrict__ T0, unsigned short* __restrict__ T1,
                     unsigned short* __restrict__ T2, unsigned short* __restrict__ T3) {
    int id = blockIdx.x, tid = threadIdx.x;

    if (id < 2048) {                              // ---- x fp32 -> bf16
        int i = id * 256 + tid;
        const float4* s4 = (const float4*)x;
        float4 a = s4[2 * i], b = s4[2 * i + 1];
        uint4 u;
        u.x = (unsigned)f2bf(a.x) | ((unsigned)f2bf(a.y) << 16);
        u.y = (unsigned)f2bf(a.z) | ((unsigned)f2bf(a.w) << 16);
        u.z = (unsigned)f2bf(b.x) | ((unsigned)f2bf(b.y) << 16);
        u.w = (unsigned)f2bf(b.z) | ((unsigned)f2bf(b.w) << 16);
        *(uint4*)(xb + 8 * (size_t)i) = u;
        return;
    }
    {                                             // ---- weight transpose+cvt
        __shared__ float t[32][33];
        int j = id - 2048, which = j >> 10, r = j & 1023;
        const float* W = (which == 0) ? W0 : (which == 1) ? W1
                         : (which == 2) ? W2 : W3;
        unsigned short* Wt = (which == 0) ? T0 : (which == 1) ? T1
                             : (which == 2) ? T2 : T3;
        int tx = tid & 31, ty = tid >> 5;          // 32 x 8
        int x0 = (r & 31) * 32, y0 = (r >> 5) * 32;
        for (int i = 0; i < 4; i++)
            t[ty + 8 * i][tx] = W[(size_t)(y0 + ty + 8 * i) * 1024 + x0 + tx];
        __syncthreads();
        for (int i = 0; i < 4; i++)
            Wt[(size_t)(x0 + ty + 8 * i) * 1024 + y0 + tx] =
                f2bf(t[tx][ty + 8 * i]);
    }
}

// ------------------------------------------------------------ QKV GEMM
// blockIdx.y < 24: GEMM blocks (which = y>>3, n-tile = y&7).
// blockIdx.y >= 24: bias-permute blocks (memory-bound, no dependency on
// the GEMM inputs) -- overlap with the compute-bound GEMM blocks.
// Bias fragment order = S^T layout (attn computes mfma(K,Q)):
//   elem (c,r) for lane (quad,l16):  q = e*64+w*16+l16, k = c*16+quad*4+r
//   -> r-inner = 4 consecutive u16 = one uint2 LDS read.
__launch_bounds__(256)
__global__ void gemm_qkv(const unsigned short* __restrict__ A,
                         const unsigned short* __restrict__ WqT,
                         const unsigned short* __restrict__ WkT,
                         const unsigned short* __restrict__ WvT,
                         const float* __restrict__ bq,
                         const float* __restrict__ bk,
                         const float* __restrict__ bv,
                         const float* __restrict__ alpha,
                         const float* __restrict__ bias2d,
                         unsigned short* __restrict__ biasP,
                         unsigned short* __restrict__ Qb,
                         unsigned short* __restrict__ Kb,
                         unsigned short* __restrict__ Vtb) {
    __shared__ __align__(16) unsigned short sh[16384];   // 32 KB union
    int tid = threadIdx.x;

    if (blockIdx.y >= 24) {            // ---------------- bias permute
        int id = blockIdx.x + 32 * (blockIdx.y - 24);    // 0..1023
        int mt = id & 31, qt = (id >> 5) & 15, b = id >> 9;
        const float* s = bias2d + (size_t)b * 2048 * 2048;
        // stage 128x64 tile as bf16*LOG2E into sh[row*68+col] (coalesced)
        for (int p = 0; p < 8; p++) {
            int row = p * 16 + (tid >> 4), f4 = tid & 15;
            float4 v = *(const float4*)
                &s[(size_t)(qt * 128 + row) * 2048 + mt * 64 + f4 * 4];
            uint2 u;
            u.x = (unsigned)f2bf(v.x * LOG2E) | ((unsigned)f2bf(v.y * LOG2E) << 16);
            u.y = (unsigned)f2bf(v.z * LOG2E) | ((unsigned)f2bf(v.w * LOG2E) << 16);
            *(uint2*)&sh[row * 68 + f4 * 4] = u;
        }
        __syncthreads();
        int w = tid >> 6, lane = tid & 63, quad = lane >> 4, l16 = lane & 15;
        unsigned short* d = biasP + (((size_t)(b * 16 + qt) * 32 + mt) * 8192);
        for (int e = 0; e < 2; e++) {
            unsigned short vals[16];
            for (int c = 0; c < 4; c++)
                *(uint2*)&vals[c * 4] = *(const uint2*)
                    &sh[(e * 64 + w * 16 + l16) * 68 + c * 16 + quad * 4];
            unsigned short* o = d + ((size_t)((e * 4 + w) * 64 + lane)) * 16;
            *(bf16x8*)&o[0] = *(bf16x8*)&vals[0];
            *(bf16x8*)&o[8] = *(bf16x8*)&vals[8];
        }
        return;
    }

    // ---------------- GEMM part
    unsigned short (*As)[64] = (unsigned short(*)[64])sh;          // [128][64]
    unsigned short (*Bs)[64] = (unsigned short(*)[64])(sh + 8192); // [128][64]
    int which = blockIdx.y >> 3;
    const unsigned short* Bt = (which == 0) ? WqT : (which == 1) ? WkT : WvT;
    const float* bias = (which == 0) ? bq : (which == 1) ? bk : bv;

    int wave = tid >> 6, lane = tid & 63, quad = lane >> 4, l16 = lane & 15;
    int wm = wave & 1, wn = wave >> 1;
    int lrow = lane >> 3, lblk = lane & 7;
    int swz = ((lblk ^ lrow) * 8);
    int m0 = blockIdx.x * 128, n0 = (blockIdx.y & 7) * 128;
    f32x4 acc[4][4] = {};

    for (int kt = 0; kt < 16; kt++) {
        int k0 = kt * 64;
        for (int i = 0; i < 4; i++) {
            int rbase = i * 32 + wave * 8;
            gload_lds16(&A[(size_t)(m0 + rbase + lrow) * 1024 + k0 + swz],
                        &As[rbase][0]);
            gload_lds16(&Bt[(size_t)(n0 + rbase + lrow) * 1024 + k0 + swz],
                        &Bs[rbase][0]);
        }
        __syncthreads();
        for (int ks = 0; ks < 2; ks++) {
            int pblk = ((ks * 4 + quad) ^ (l16 & 7)) * 8;
            bf16x8 af[4], bf_[4];
            for (int i = 0; i < 4; i++)
                af[i] = *(const bf16x8*)&As[64 * wm + 16 * i + l16][pblk];
            for (int j = 0; j < 4; j++)
                bf_[j] = *(const bf16x8*)&Bs[64 * wn + 16 * j + l16][pblk];
            if (which == 2) {
                for (int i = 0; i < 4; i++)
                    for (int j = 0; j < 4; j++)
                        acc[i][j] = __builtin_amdgcn_mfma_f32_16x16x32_bf16(
                            af[i], bf_[j], acc[i][j], 0, 0, 0);
            } else {   // swapped: acc[i][j] = C^T block (row=weight col, col=token)
                for (int i = 0; i < 4; i++)
                    for (int j = 0; j < 4; j++)
                        acc[i][j] = __builtin_amdgcn_mfma_f32_16x16x32_bf16(
                            bf_[j], af[i], acc[i][j], 0, 0, 0);
            }
        }
        __syncthreads();
    }

    if (which == 2) {
        for (int i = 0; i < 4; i++)
            for (int j = 0; j < 4; j++) {
                int colb = n0 + 64 * wn + 16 * j + l16;
                int h = colb >> 6, dk = colb & 63;
                int row0 = m0 + 64 * wm + 16 * i + quad * 4;
                int bb = row0 >> 11, nn0 = row0 & 2047;
                unsigned short v4[4];
                for (int r = 0; r < 4; r++) {
                    float v = acc[i][j][r] + bias[colb];
                    v4[r] = f2bf(v * (1.0f + alpha[bb * 2048 + nn0 + r]));
                }
                uint2 u;
                u.x = (unsigned)v4[0] | ((unsigned)v4[1] << 16);
                u.y = (unsigned)v4[2] | ((unsigned)v4[3] << 16);
                *(uint2*)&Vtb[((size_t)(bb * 16 + h) * 64 + dk) * 2048 + nn0] = u;
            }
    } else {
        unsigned short* outb = (which == 0) ? Qb : Kb;
        for (int i = 0; i < 4; i++)
            for (int j = 0; j < 4; j++) {
                int row = m0 + 64 * wm + 16 * i + l16;          // token
                int bb = row >> 11, nn = row & 2047;
                int colb0 = n0 + 64 * wn + 16 * j + quad * 4;   // 4 consec cols
                int h = colb0 >> 6, dk0 = colb0 & 63;
                float4 b4 = *(const float4*)&bias[colb0];
                float s = (which == 0) ? (0.125f * LOG2E)
                                       : (1.0f + alpha[bb * 2048 + nn]);
                unsigned short v4[4];
                v4[0] = f2bf((acc[i][j][0] + b4.x) * s);
                v4[1] = f2bf((acc[i][j][1] + b4.y) * s);
                v4[2] = f2bf((acc[i][j][2] + b4.z) * s);
                v4[3] = f2bf((acc[i][j][3] + b4.w) * s);
                uint2 u;
                u.x = (unsigned)v4[0] | ((unsigned)v4[1] << 16);
                u.y = (unsigned)v4[2] | ((unsigned)v4[3] << 16);
                *(uint2*)&outb[((size_t)(bb * 16 + h) * 2048 + nn) * 64 + dk0] = u;
            }
    }
}

// ------------------------------------------------ out projection GEMM (fp32)
// 128x64 tiles -> grid (32,16) = 512 blocks = 2 blocks/CU.
__launch_bounds__(256)
__global__ void gemm_out(const unsigned short* __restrict__ A,
                         const unsigned short* __restrict__ Bt,
                         const float* __restrict__ bias,
                         float* __restrict__ outf) {
    __shared__ __align__(16) unsigned short As[128][64];   // 16 KB
    __shared__ __align__(16) unsigned short Bs[64][64];    //  8 KB
    int tid = threadIdx.x;
    int wave = tid >> 6, lane = tid & 63, quad = lane >> 4, l16 = lane & 15;
    int wm = wave & 1, wn = wave >> 1;        // wn in 0..1
    int lrow = lane >> 3, lblk = lane & 7;
    int swz = ((lblk ^ lrow) * 8);
    int m0 = blockIdx.x * 128, n0 = blockIdx.y * 64;
    f32x4 acc[4][2] = {};

    for (int kt = 0; kt < 16; kt++) {
        int k0 = kt * 64;
        for (int i = 0; i < 4; i++) {
            int rbase = i * 32 + wave * 8;
            gload_lds16(&A[(size_t)(m0 + rbase + lrow) * 1024 + k0 + swz],
                        &As[rbase][0]);
        }
        for (int i = 0; i < 2; i++) {
            int rbase = i * 32 + wave * 8;
            gload_lds16(&Bt[(size_t)(n0 + rbase + lrow) * 1024 + k0 + swz],
                        &Bs[rbase][0]);
        }
        __syncthreads();
        for (int ks = 0; ks < 2; ks++) {
            int pblk = ((ks * 4 + quad) ^ (l16 & 7)) * 8;
            bf16x8 af[4], bf_[2];
            for (int i = 0; i < 4; i++)
                af[i] = *(const bf16x8*)&As[64 * wm + 16 * i + l16][pblk];
            for (int j = 0; j < 2; j++)
                bf_[j] = *(const bf16x8*)&Bs[32 * wn + 16 * j + l16][pblk];
            for (int i = 0; i < 4; i++)
                for (int j = 0; j < 2; j++)
                    acc[i][j] = __builtin_amdgcn_mfma_f32_16x16x32_bf16(
                        bf_[j], af[i], acc[i][j], 0, 0, 0);
        }
        __syncthreads();
    }

    for (int i = 0; i < 4; i++)
        for (int j = 0; j < 2; j++) {
            int row = m0 + 64 * wm + 16 * i + l16;          // token
            int colb0 = n0 + 32 * wn + 16 * j + quad * 4;   // 4 consec cols
            float4 b4 = *(const float4*)&bias[colb0];
            float4 o;
            o.x = acc[i][j][0] + b4.x;
            o.y = acc[i][j][1] + b4.y;
            o.z = acc[i][j][2] + b4.z;
            o.w = acc[i][j][3] + b4.w;
            *(float4*)&outf[(size_t)row * 1024 + colb0] = o;
        }
}

// ----------------------------------------------------- flash attention
// Round-10 structure (S^T QK, packed b64 P-stores) with the P-block
// rotation changed l16>>2 -> l16>>1.  Derivation: write bank-pair =
// 2*((l16 + f(l16) + kc) mod 8) + q1; uniformity needs (l16+f(l16)) mod 8
// flat.  f=l16>>2 gives histogram {3,2,3,2,1,2,1,2} (6 accesses on hot
// banks vs 4 floor -> the 5.5M conflicts); f=l16>>1 gives {2,...,2} ->
// writes AND b128 reads both land exactly on the bandwidth floor.
__launch_bounds__(256, 4)
__global__ void attn_kernel(const unsigned short* __restrict__ Q,
                            const unsigned short* __restrict__ K,
                            const unsigned short* __restrict__ Vt,
                            const unsigned short* __restrict__ biasP,
                            unsigned short* __restrict__ Y,
                            float* __restrict__ Opart,
                            float* __restrict__ Lpart, int split) {
    __shared__ __align__(16) unsigned short Ks[64][64];
    __shared__ __align__(16) unsigned short Vs[64][64];
    __shared__ __align__(16) unsigned short Ps[4][32][72];
    int tid = threadIdx.x;
    int wave = tid >> 6, lane = tid & 63, quad = lane >> 4, l16 = lane & 15;
    int qt = blockIdx.x, h = blockIdx.y;
    int b, mt0, mtN;
    if (split) { b = blockIdx.z >> 1; int half = blockIdx.z & 1;
                 mt0 = half * 16; mtN = mt0 + 16; }
    else       { b = blockIdx.z; mt0 = 0; mtN = 32; }
    int q0 = qt * 128;
    size_t headoff = (size_t)(b * 16 + h) * 2048 * 64;
    const unsigned short* Kp = K + headoff;
    const unsigned short* Vp = Vt + headoff;
    int lrow = lane >> 3, lblk = lane & 7;
    int swz = (lblk ^ lrow) * 8;

    bf16x8 aq[2][2];
    for (int e = 0; e < 2; e++) {
        const unsigned short* qp =
            Q + headoff + (size_t)(q0 + e * 64 + wave * 16 + l16) * 64;
        aq[e][0] = *(const bf16x8*)&qp[quad * 8];
        aq[e][1] = *(const bf16x8*)&qp[32 + quad * 8];
    }
    bf16x8 ones;
    for (int j = 0; j < 8; j++) ones[j] = (short)0x3F80;   // bf16 1.0

    f32x4 oacc[2][4] = {};
    f32x4 lacc[2] = {};
    const unsigned short* bP = biasP + (size_t)(b * 16 + qt) * 32 * 8192;

    for (int mt = mt0; mt < mtN; mt++) {
        int m0 = mt * 64;
        for (int i = 0; i < 2; i++) {
            int rbase = wave * 16 + i * 8;
            gload_lds16(&Kp[(size_t)(m0 + rbase + lrow) * 64 + swz], &Ks[rbase][0]);
            gload_lds16(&Vp[(size_t)(rbase + lrow) * 2048 + m0 + swz], &Vs[rbase][0]);
        }
        const unsigned short* bt = bP + (size_t)mt * 8192;
        bf16x8 bz[2][2];
        for (int e = 0; e < 2; e++) {
            const unsigned short* p = bt + (size_t)((e * 4 + wave) * 64 + lane) * 16;
            bz[e][0] = *(const bf16x8*)&p[0];
            bz[e][1] = *(const bf16x8*)&p[8];
        }
        __syncthreads();

        // S^T = bias^T + (Q K^T)^T : operands swapped so lane (quad,l16)
        // holds q = l16, k = c*16 + quad*4 + r  (4 consecutive k).
        f32x4 sc[2][4];
        for (int e = 0; e < 2; e++)
            for (int c = 0; c < 4; c++) {
                uint2 w = ((const uint2*)&bz[e][c >> 1])[c & 1];
                f32x4 s;
                s[0] = __builtin_bit_cast(float, w.x << 16);
                s[1] = __builtin_bit_cast(float, w.x & 0xffff0000u);
                s[2] = __builtin_bit_cast(float, w.y << 16);
                s[3] = __builtin_bit_cast(float, w.y & 0xffff0000u);
                sc[e][c] = s;
            }
        __builtin_amdgcn_s_setprio(1);
        for (int c = 0; c < 4; c++) {
            for (int ks = 0; ks < 2; ks++) {
                bf16x8 kf = *(const bf16x8*)&Ks[c * 16 + l16]
                                               [((ks * 4 + quad) ^ (l16 & 7)) * 8];
                sc[0][c] = __builtin_amdgcn_mfma_f32_16x16x32_bf16(kf, aq[0][ks], sc[0][c], 0, 0, 0);
                sc[1][c] = __builtin_amdgcn_mfma_f32_16x16x32_bf16(kf, aq[1][ks], sc[1][c], 0, 0, 0);
            }
        }
        __builtin_amdgcn_s_setprio(0);

        // P = exp2(S) -> Ps, packed 8B stores (truncated bf16).
        // Row = e*16 + l16 (q); block rotation f(l16) = l16>>1 (balanced).
        for (int e = 0; e < 2; e++)
            for (int c = 0; c < 4; c++) {
                unsigned int b0 = __builtin_bit_cast(unsigned int, exp2_raw(sc[e][c][0]));
                unsigned int b1 = __builtin_bit_cast(unsigned int, exp2_raw(sc[e][c][1]));
                unsigned int b2 = __builtin_bit_cast(unsigned int, exp2_raw(sc[e][c][2]));
                unsigned int b3 = __builtin_bit_cast(unsigned int, exp2_raw(sc[e][c][3]));
                uint2 u;
                u.x = (b0 >> 16) | (b1 & 0xffff0000u);
                u.y = (b2 >> 16) | (b3 & 0xffff0000u);
                int pb = ((c * 2 + (quad >> 1)) + (l16 >> 1)) & 7;
                *(uint2*)&Ps[wave][e * 16 + l16][pb * 8 + (quad & 1) * 4] = u;
            }

        // O += P V ; l += P 1   (read rotation matches: l16>>1)
        __builtin_amdgcn_s_setprio(1);
        for (int ks = 0; ks < 2; ks++) {
            int blkr = (ks * 4 + quad + (l16 >> 1)) & 7;
            bf16x8 pf0 = *(const bf16x8*)&Ps[wave][l16][blkr * 8];
            bf16x8 pf1 = *(const bf16x8*)&Ps[wave][16 + l16][blkr * 8];
            lacc[0] = __builtin_amdgcn_mfma_f32_16x16x32_bf16(pf0, ones, lacc[0], 0, 0, 0);
            lacc[1] = __builtin_amdgcn_mfma_f32_16x16x32_bf16(pf1, ones, lacc[1], 0, 0, 0);
            for (int cv = 0; cv < 4; cv++) {
                bf16x8 vf = *(const bf16x8*)&Vs[cv * 16 + l16]
                                               [((ks * 4 + quad) ^ (l16 & 7)) * 8];
                oacc[0][cv] = __builtin_amdgcn_mfma_f32_16x16x32_bf16(pf0, vf, oacc[0][cv], 0, 0, 0);
                oacc[1][cv] = __builtin_amdgcn_mfma_f32_16x16x32_bf16(pf1, vf, oacc[1][cv], 0, 0, 0);
            }
        }
        __builtin_amdgcn_s_setprio(0);
        __syncthreads();
    }

    if (split) {
        size_t p = ((size_t)((b * 16 + h) * 16 + qt)) * 2 + (blockIdx.z & 1);
        float* Op = Opart + p * 8192;
        for (int e = 0; e < 2; e++)
            for (int cv = 0; cv < 4; cv++)
                for (int r = 0; r < 4; r++)
                    Op[(e * 64 + wave * 16 + quad * 4 + r) * 64 + cv * 16 + l16] =
                        oacc[e][cv][r];
        if (l16 == 0)
            for (int e = 0; e < 2; e++)
                for (int r = 0; r < 4; r++)
                    Lpart[p * 128 + e * 64 + wave * 16 + quad * 4 + r] = lacc[e][r];
    } else {
        for (int e = 0; e < 2; e++) {
            float invl[4];
            for (int r = 0; r < 4; r++) invl[r] = 1.0f / lacc[e][r];
            for (int cv = 0; cv < 4; cv++)
                for (int r = 0; r < 4; r++) {
                    int qrow = q0 + e * 64 + 16 * wave + quad * 4 + r;
                    int d = h * 64 + cv * 16 + l16;
                    Y[((size_t)b * 2048 + qrow) * 1024 + d] =
                        f2bf(oacc[e][cv][r] * invl[r]);
                }
        }
    }
}

// -------------------------------------------- combine split-K partials -> Y
__global__ void attn_combine(const float* __restrict__ Opart,
                             const float* __restrict__ Lpart,
                             unsigned short* __restrict__ Y) {
    int blk = blockIdx.x;                    // (b*16+h)*16+qt, 512 blocks
    int qt = blk & 15, h = (blk >> 4) & 15, b = blk >> 8;
    const float* O0 = Opart + (size_t)blk * 2 * 8192;
    const float* O1 = O0 + 8192;
    const float* L0 = Lpart + (size_t)blk * 2 * 128;
    const float* L1 = L0 + 128;
    int t = threadIdx.x;
    for (int i = 0; i < 8; i++) {
        int idx4 = i * 256 + t;              // float4 index (2048 total)
        int q = idx4 >> 4;
        int dk = (idx4 & 15) * 4;
        float4 a = *(const float4*)&O0[idx4 * 4];
        float4 c = *(const float4*)&O1[idx4 * 4];
        float inv = 1.0f / (L0[q] + L1[q]);
        uint2 u;
        u.x = (unsigned)f2bf((a.x + c.x) * inv) |
              ((unsigned)f2bf((a.y + c.y) * inv) << 16);
        u.y = (unsigned)f2bf((a.z + c.z) * inv) |
              ((unsigned)f2bf((a.w + c.w) * inv) << 16);
        int qrow = qt * 128 + q;
        *(uint2*)&Y[((size_t)b * 2048 + qrow) * 1024 + h * 64 + dk] = u;
    }
}

// ---------------------------------------------------------------- launcher
extern "C" void kernel_launch(void* const* d_in, const int* in_sizes, int n_in,
                              void* d_out, int out_size, void* d_ws, size_t ws_size,
                              hipStream_t stream) {
    const float* x     = (const float*)d_in[0];
    const float* alpha = (const float*)d_in[1];
    const float* bias  = (const float*)d_in[2];
    const float* Wq    = (const float*)d_in[3];
    const float* bq    = (const float*)d_in[4];
    const float* Wk    = (const float*)d_in[5];
    const float* bk    = (const float*)d_in[6];
    const float* Wv    = (const float*)d_in[7];
    const float* bv    = (const float*)d_in[8];
    const float* Wo    = (const float*)d_in[9];
    const float* bo    = (const float*)d_in[10];
    float* out = (float*)d_out;

    char* ws = (char*)d_ws;
    const size_t MB = 1048576;
    unsigned short* xb    = (unsigned short*)(ws);            // [0,8M), Yb later
    unsigned short* wqt   = (unsigned short*)(ws + 8 * MB);
    unsigned short* wkt   = (unsigned short*)(ws + 10 * MB);
    unsigned short* wvt   = (unsigned short*)(ws + 12 * MB);
    unsigned short* wot   = (unsigned short*)(ws + 14 * MB);
    unsigned short* Qb    = (unsigned short*)(ws + 16 * MB);
    unsigned short* Kb    = (unsigned short*)(ws + 24 * MB);
    unsigned short* Vtb   = (unsigned short*)(ws + 32 * MB);
    unsigned short* biasP = (unsigned short*)(ws + 40 * MB);  // 16 MB
    float*          Opart = (float*)(ws + 56 * MB);           // 32 MB
    float*          Lpart = (float*)(ws + 88 * MB);           // 0.5 MB
    unsigned short* Yb    = xb;
    int split = (ws_size >= 90 * MB) ? 1 : 0;

    prep<<<6144, 256, 0, stream>>>(x, xb, Wq, Wk, Wv, Wo, wqt, wkt, wvt, wot);

    // GEMM blocks (y<24) + bias-permute blocks (y>=24, overlapped)
    gemm_qkv<<<dim3(32, 56), 256, 0, stream>>>(
        xb, wqt, wkt, wvt, bq, bk, bv, alpha, bias, biasP, Qb, Kb, Vtb);

    if (split) {
        attn_kernel<<<dim3(16, 16, 4), 256, 0, stream>>>(
            Qb, Kb, Vtb, biasP, Yb, Opart, Lpart, 1);
        attn_combine<<<512, 256, 0, stream>>>(Opart, Lpart, Yb);
    } else {
        attn_kernel<<<dim3(16, 16, 2), 256, 0, stream>>>(
            Qb, Kb, Vtb, biasP, Yb, Opart, Lpart, 0);
    }

    gemm_out<<<dim3(32, 16), 256, 0, stream>>>(Yb, wot, bo, out);
}

// Round 12
// 221.405 us; speedup vs baseline: 1.0508x; 1.0272x over previous
//
#include <hip/hip_runtime.h>

typedef __attribute__((ext_vector_type(8))) short bf16x8;
typedef __attribute__((ext_vector_type(4))) float f32x4;

#define LOG2E 1.4426950408889634f

static __device__ __forceinline__ unsigned short f2bf(float f) {
    unsigned int u = __builtin_bit_cast(unsigned int, f);
    u += 0x7fffu + ((u >> 16) & 1u);   // round-to-nearest-even
    return (unsigned short)(u >> 16);
}
// raw v_exp_f32: skips OCML's denormal-range fixup (S is bounded, |S|<~30)
static __device__ __forceinline__ float exp2_raw(float x) {
    float r;
    asm("v_exp_f32 %0, %1" : "=v"(r) : "v"(x));
    return r;
}
// async global->LDS, 16B per lane; LDS dest = wave-uniform base + lane*16
static __device__ __forceinline__ void gload_lds16(const void* g, void* l) {
    __builtin_amdgcn_global_load_lds(
        (const __attribute__((address_space(1))) void*)g,
        (__attribute__((address_space(3))) void*)l, 16, 0, 0);
}

// ---------------- preprocessing: convert x (blocks 0..2047),
// ---------------- transpose+convert 4 weights (blocks 2048..6143)
__launch_bounds__(256)
__global__ void prep(const float* __restrict__ x,
                     unsigned short* __restrict__ xb,
                     const float* __restrict__ W0, const float* __restrict__ W1,
                     const float* __restrict__ W2, const float* __restrict__ W3,
                     unsigned short* __restrict__ T0, unsigned short* __restrict__ T1,
                     unsigned short* __restrict__ T2, unsigned short* __restrict__ T3) {
    int id = blockIdx.x, tid = threadIdx.x;

    if (id < 2048) {                              // ---- x fp32 -> bf16
        int i = id * 256 + tid;
        const float4* s4 = (const float4*)x;
        float4 a = s4[2 * i], b = s4[2 * i + 1];
        uint4 u;
        u.x = (unsigned)f2bf(a.x) | ((unsigned)f2bf(a.y) << 16);
        u.y = (unsigned)f2bf(a.z) | ((unsigned)f2bf(a.w) << 16);
        u.z = (unsigned)f2bf(b.x) | ((unsigned)f2bf(b.y) << 16);
        u.w = (unsigned)f2bf(b.z) | ((unsigned)f2bf(b.w) << 16);
        *(uint4*)(xb + 8 * (size_t)i) = u;
        return;
    }
    {                                             // ---- weight transpose+cvt
        __shared__ float t[32][33];
        int j = id - 2048, which = j >> 10, r = j & 1023;
        const float* W = (which == 0) ? W0 : (which == 1) ? W1
                         : (which == 2) ? W2 : W3;
        unsigned short* Wt = (which == 0) ? T0 : (which == 1) ? T1
                             : (which == 2) ? T2 : T3;
        int tx = tid & 31, ty = tid >> 5;          // 32 x 8
        int x0 = (r & 31) * 32, y0 = (r >> 5) * 32;
        for (int i = 0; i < 4; i++)
            t[ty + 8 * i][tx] = W[(size_t)(y0 + ty + 8 * i) * 1024 + x0 + tx];
        __syncthreads();
        for (int i = 0; i < 4; i++)
            Wt[(size_t)(x0 + ty + 8 * i) * 1024 + y0 + tx] =
                f2bf(t[tx][ty + 8 * i]);
    }
}

// ------------------------------------------------------------ QKV GEMM
// blockIdx.y < 24: GEMM blocks (which = y>>3, n-tile = y&7).
// blockIdx.y >= 24: bias-permute blocks (memory-bound, no dependency on
// the GEMM inputs) -- overlap with the compute-bound GEMM blocks.
// Bias fragment order = S^T layout (attn computes mfma(K,Q)):
//   elem (c,r) for lane (quad,l16):  q = e*64+w*16+l16, k = c*16+quad*4+r
//   -> r-inner = 4 consecutive u16 = one uint2 LDS read.
__launch_bounds__(256)
__global__ void gemm_qkv(const unsigned short* __restrict__ A,
                         const unsigned short* __restrict__ WqT,
                         const unsigned short* __restrict__ WkT,
                         const unsigned short* __restrict__ WvT,
                         const float* __restrict__ bq,
                         const float* __restrict__ bk,
                         const float* __restrict__ bv,
                         const float* __restrict__ alpha,
                         const float* __restrict__ bias2d,
                         unsigned short* __restrict__ biasP,
                         unsigned short* __restrict__ Qb,
                         unsigned short* __restrict__ Kb,
                         unsigned short* __restrict__ Vtb) {
    __shared__ __align__(16) unsigned short sh[16384];   // 32 KB union
    int tid = threadIdx.x;

    if (blockIdx.y >= 24) {            // ---------------- bias permute
        int id = blockIdx.x + 32 * (blockIdx.y - 24);    // 0..1023
        int mt = id & 31, qt = (id >> 5) & 15, b = id >> 9;
        const float* s = bias2d + (size_t)b * 2048 * 2048;
        // stage 128x64 tile as bf16*LOG2E into sh[row*68+col] (coalesced)
        for (int p = 0; p < 8; p++) {
            int row = p * 16 + (tid >> 4), f4 = tid & 15;
            float4 v = *(const float4*)
                &s[(size_t)(qt * 128 + row) * 2048 + mt * 64 + f4 * 4];
            uint2 u;
            u.x = (unsigned)f2bf(v.x * LOG2E) | ((unsigned)f2bf(v.y * LOG2E) << 16);
            u.y = (unsigned)f2bf(v.z * LOG2E) | ((unsigned)f2bf(v.w * LOG2E) << 16);
            *(uint2*)&sh[row * 68 + f4 * 4] = u;
        }
        __syncthreads();
        int w = tid >> 6, lane = tid & 63, quad = lane >> 4, l16 = lane & 15;
        unsigned short* d = biasP + (((size_t)(b * 16 + qt) * 32 + mt) * 8192);
        for (int e = 0; e < 2; e++) {
            unsigned short vals[16];
            for (int c = 0; c < 4; c++)
                *(uint2*)&vals[c * 4] = *(const uint2*)
                    &sh[(e * 64 + w * 16 + l16) * 68 + c * 16 + quad * 4];
            unsigned short* o = d + ((size_t)((e * 4 + w) * 64 + lane)) * 16;
            *(bf16x8*)&o[0] = *(bf16x8*)&vals[0];
            *(bf16x8*)&o[8] = *(bf16x8*)&vals[8];
        }
        return;
    }

    // ---------------- GEMM part
    unsigned short (*As)[64] = (unsigned short(*)[64])sh;          // [128][64]
    unsigned short (*Bs)[64] = (unsigned short(*)[64])(sh + 8192); // [128][64]
    int which = blockIdx.y >> 3;
    const unsigned short* Bt = (which == 0) ? WqT : (which == 1) ? WkT : WvT;
    const float* bias = (which == 0) ? bq : (which == 1) ? bk : bv;

    int wave = tid >> 6, lane = tid & 63, quad = lane >> 4, l16 = lane & 15;
    int wm = wave & 1, wn = wave >> 1;
    int lrow = lane >> 3, lblk = lane & 7;
    int swz = ((lblk ^ lrow) * 8);
    int m0 = blockIdx.x * 128, n0 = (blockIdx.y & 7) * 128;
    f32x4 acc[4][4] = {};

    for (int kt = 0; kt < 16; kt++) {
        int k0 = kt * 64;
        for (int i = 0; i < 4; i++) {
            int rbase = i * 32 + wave * 8;
            gload_lds16(&A[(size_t)(m0 + rbase + lrow) * 1024 + k0 + swz],
                        &As[rbase][0]);
            gload_lds16(&Bt[(size_t)(n0 + rbase + lrow) * 1024 + k0 + swz],
                        &Bs[rbase][0]);
        }
        __syncthreads();
        for (int ks = 0; ks < 2; ks++) {
            int pblk = ((ks * 4 + quad) ^ (l16 & 7)) * 8;
            bf16x8 af[4], bf_[4];
            for (int i = 0; i < 4; i++)
                af[i] = *(const bf16x8*)&As[64 * wm + 16 * i + l16][pblk];
            for (int j = 0; j < 4; j++)
                bf_[j] = *(const bf16x8*)&Bs[64 * wn + 16 * j + l16][pblk];
            if (which == 2) {
                for (int i = 0; i < 4; i++)
                    for (int j = 0; j < 4; j++)
                        acc[i][j] = __builtin_amdgcn_mfma_f32_16x16x32_bf16(
                            af[i], bf_[j], acc[i][j], 0, 0, 0);
            } else {   // swapped: acc[i][j] = C^T block (row=weight col, col=token)
                for (int i = 0; i < 4; i++)
                    for (int j = 0; j < 4; j++)
                        acc[i][j] = __builtin_amdgcn_mfma_f32_16x16x32_bf16(
                            bf_[j], af[i], acc[i][j], 0, 0, 0);
            }
        }
        __syncthreads();
    }

    if (which == 2) {
        for (int i = 0; i < 4; i++)
            for (int j = 0; j < 4; j++) {
                int colb = n0 + 64 * wn + 16 * j + l16;
                int h = colb >> 6, dk = colb & 63;
                int row0 = m0 + 64 * wm + 16 * i + quad * 4;
                int bb = row0 >> 11, nn0 = row0 & 2047;
                unsigned short v4[4];
                for (int r = 0; r < 4; r++) {
                    float v = acc[i][j][r] + bias[colb];
                    v4[r] = f2bf(v * (1.0f + alpha[bb * 2048 + nn0 + r]));
                }
                uint2 u;
                u.x = (unsigned)v4[0] | ((unsigned)v4[1] << 16);
                u.y = (unsigned)v4[2] | ((unsigned)v4[3] << 16);
                *(uint2*)&Vtb[((size_t)(bb * 16 + h) * 64 + dk) * 2048 + nn0] = u;
            }
    } else {
        unsigned short* outb = (which == 0) ? Qb : Kb;
        for (int i = 0; i < 4; i++)
            for (int j = 0; j < 4; j++) {
                int row = m0 + 64 * wm + 16 * i + l16;          // token
                int bb = row >> 11, nn = row & 2047;
                int colb0 = n0 + 64 * wn + 16 * j + quad * 4;   // 4 consec cols
                int h = colb0 >> 6, dk0 = colb0 & 63;
                float4 b4 = *(const float4*)&bias[colb0];
                float s = (which == 0) ? (0.125f * LOG2E)
                                       : (1.0f + alpha[bb * 2048 + nn]);
                unsigned short v4[4];
                v4[0] = f2bf((acc[i][j][0] + b4.x) * s);
                v4[1] = f2bf((acc[i][j][1] + b4.y) * s);
                v4[2] = f2bf((acc[i][j][2] + b4.z) * s);
                v4[3] = f2bf((acc[i][j][3] + b4.w) * s);
                uint2 u;
                u.x = (unsigned)v4[0] | ((unsigned)v4[1] << 16);
                u.y = (unsigned)v4[2] | ((unsigned)v4[3] << 16);
                *(uint2*)&outb[((size_t)(bb * 16 + h) * 2048 + nn) * 64 + dk0] = u;
            }
    }
}

// ------------------------------------------------ out projection GEMM (fp32)
// 128x64 tiles -> grid (32,16) = 512 blocks = 2 blocks/CU.
__launch_bounds__(256)
__global__ void gemm_out(const unsigned short* __restrict__ A,
                         const unsigned short* __restrict__ Bt,
                         const float* __restrict__ bias,
                         float* __restrict__ outf) {
    __shared__ __align__(16) unsigned short As[128][64];   // 16 KB
    __shared__ __align__(16) unsigned short Bs[64][64];    //  8 KB
    int tid = threadIdx.x;
    int wave = tid >> 6, lane = tid & 63, quad = lane >> 4, l16 = lane & 15;
    int wm = wave & 1, wn = wave >> 1;        // wn in 0..1
    int lrow = lane >> 3, lblk = lane & 7;
    int swz = ((lblk ^ lrow) * 8);
    int m0 = blockIdx.x * 128, n0 = blockIdx.y * 64;
    f32x4 acc[4][2] = {};

    for (int kt = 0; kt < 16; kt++) {
        int k0 = kt * 64;
        for (int i = 0; i < 4; i++) {
            int rbase = i * 32 + wave * 8;
            gload_lds16(&A[(size_t)(m0 + rbase + lrow) * 1024 + k0 + swz],
                        &As[rbase][0]);
        }
        for (int i = 0; i < 2; i++) {
            int rbase = i * 32 + wave * 8;
            gload_lds16(&Bt[(size_t)(n0 + rbase + lrow) * 1024 + k0 + swz],
                        &Bs[rbase][0]);
        }
        __syncthreads();
        for (int ks = 0; ks < 2; ks++) {
            int pblk = ((ks * 4 + quad) ^ (l16 & 7)) * 8;
            bf16x8 af[4], bf_[2];
            for (int i = 0; i < 4; i++)
                af[i] = *(const bf16x8*)&As[64 * wm + 16 * i + l16][pblk];
            for (int j = 0; j < 2; j++)
                bf_[j] = *(const bf16x8*)&Bs[32 * wn + 16 * j + l16][pblk];
            for (int i = 0; i < 4; i++)
                for (int j = 0; j < 2; j++)
                    acc[i][j] = __builtin_amdgcn_mfma_f32_16x16x32_bf16(
                        bf_[j], af[i], acc[i][j], 0, 0, 0);
        }
        __syncthreads();
    }

    for (int i = 0; i < 4; i++)
        for (int j = 0; j < 2; j++) {
            int row = m0 + 64 * wm + 16 * i + l16;          // token
            int colb0 = n0 + 32 * wn + 16 * j + quad * 4;   // 4 consec cols
            float4 b4 = *(const float4*)&bias[colb0];
            float4 o;
            o.x = acc[i][j][0] + b4.x;
            o.y = acc[i][j][1] + b4.y;
            o.z = acc[i][j][2] + b4.z;
            o.w = acc[i][j][3] + b4.w;
            *(float4*)&outf[(size_t)row * 1024 + colb0] = o;
        }
}

// ----------------------------------------------------- flash attention
// Round-11 structure (S^T QK, packed b64 P-stores, l16>>1 rotation) +
// XCD-affinity block remap: dispatch round-robins XCDs by linear block id
// (id%8), which spreads the 16 qt-blocks sharing one K/V (half-)panel
// across all 8 XCDs (each L2 misses -> L3).  Remap so each XCD owns
// complete 16-qt groups: per-XCD K/V working set = 8 groups x 256 KB =
// 2 MB < 4 MB L2 -> K/V re-reads become L2 hits.  Bijective (1024/512
// blocks), correctness-independent of the actual dispatch rule.
__launch_bounds__(256, 4)
__global__ void attn_kernel(const unsigned short* __restrict__ Q,
                            const unsigned short* __restrict__ K,
                            const unsigned short* __restrict__ Vt,
                            const unsigned short* __restrict__ biasP,
                            unsigned short* __restrict__ Y,
                            float* __restrict__ Opart,
                            float* __restrict__ Lpart, int split) {
    __shared__ __align__(16) unsigned short Ks[64][64];
    __shared__ __align__(16) unsigned short Vs[64][64];
    __shared__ __align__(16) unsigned short Ps[4][32][72];
    int tid = threadIdx.x;
    int wave = tid >> 6, lane = tid & 63, quad = lane >> 4, l16 = lane & 15;

    int lin = blockIdx.x + 16 * (blockIdx.y + 16 * blockIdx.z);
    int xcd = lin & 7, slot = lin >> 3;
    int qt = slot & 15;
    int h, b, mt0, mtN, half = 0;
    if (split) {                 // 1024 blocks: 64 (h,half,b) groups, 8/XCD
        int g = xcd * 8 + (slot >> 4);
        h = g & 15; half = (g >> 4) & 1; b = g >> 5;
        mt0 = half * 16; mtN = mt0 + 16;
    } else {                     // 512 blocks: 32 (h,b) groups, 4/XCD
        int g = xcd * 4 + (slot >> 4);
        h = g & 15; b = g >> 4;
        mt0 = 0; mtN = 32;
    }
    int q0 = qt * 128;
    size_t headoff = (size_t)(b * 16 + h) * 2048 * 64;
    const unsigned short* Kp = K + headoff;
    const unsigned short* Vp = Vt + headoff;
    int lrow = lane >> 3, lblk = lane & 7;
    int swz = (lblk ^ lrow) * 8;

    bf16x8 aq[2][2];
    for (int e = 0; e < 2; e++) {
        const unsigned short* qp =
            Q + headoff + (size_t)(q0 + e * 64 + wave * 16 + l16) * 64;
        aq[e][0] = *(const bf16x8*)&qp[quad * 8];
        aq[e][1] = *(const bf16x8*)&qp[32 + quad * 8];
    }
    bf16x8 ones;
    for (int j = 0; j < 8; j++) ones[j] = (short)0x3F80;   // bf16 1.0

    f32x4 oacc[2][4] = {};
    f32x4 lacc[2] = {};
    const unsigned short* bP = biasP + (size_t)(b * 16 + qt) * 32 * 8192;

    for (int mt = mt0; mt < mtN; mt++) {
        int m0 = mt * 64;
        for (int i = 0; i < 2; i++) {
            int rbase = wave * 16 + i * 8;
            gload_lds16(&Kp[(size_t)(m0 + rbase + lrow) * 64 + swz], &Ks[rbase][0]);
            gload_lds16(&Vp[(size_t)(rbase + lrow) * 2048 + m0 + swz], &Vs[rbase][0]);
        }
        const unsigned short* bt = bP + (size_t)mt * 8192;
        bf16x8 bz[2][2];
        for (int e = 0; e < 2; e++) {
            const unsigned short* p = bt + (size_t)((e * 4 + wave) * 64 + lane) * 16;
            bz[e][0] = *(const bf16x8*)&p[0];
            bz[e][1] = *(const bf16x8*)&p[8];
        }
        __syncthreads();

        // S^T = bias^T + (Q K^T)^T : operands swapped so lane (quad,l16)
        // holds q = l16, k = c*16 + quad*4 + r  (4 consecutive k).
        f32x4 sc[2][4];
        for (int e = 0; e < 2; e++)
            for (int c = 0; c < 4; c++) {
                uint2 w = ((const uint2*)&bz[e][c >> 1])[c & 1];
                f32x4 s;
                s[0] = __builtin_bit_cast(float, w.x << 16);
                s[1] = __builtin_bit_cast(float, w.x & 0xffff0000u);
                s[2] = __builtin_bit_cast(float, w.y << 16);
                s[3] = __builtin_bit_cast(float, w.y & 0xffff0000u);
                sc[e][c] = s;
            }
        __builtin_amdgcn_s_setprio(1);
        for (int c = 0; c < 4; c++) {
            for (int ks = 0; ks < 2; ks++) {
                bf16x8 kf = *(const bf16x8*)&Ks[c * 16 + l16]
                                               [((ks * 4 + quad) ^ (l16 & 7)) * 8];
                sc[0][c] = __builtin_amdgcn_mfma_f32_16x16x32_bf16(kf, aq[0][ks], sc[0][c], 0, 0, 0);
                sc[1][c] = __builtin_amdgcn_mfma_f32_16x16x32_bf16(kf, aq[1][ks], sc[1][c], 0, 0, 0);
            }
        }
        __builtin_amdgcn_s_setprio(0);

        // P = exp2(S) -> Ps, packed 8B stores (truncated bf16).
        // Row = e*16 + l16 (q); block rotation f(l16) = l16>>1 (balanced).
        for (int e = 0; e < 2; e++)
            for (int c = 0; c < 4; c++) {
                unsigned int b0 = __builtin_bit_cast(unsigned int, exp2_raw(sc[e][c][0]));
                unsigned int b1 = __builtin_bit_cast(unsigned int, exp2_raw(sc[e][c][1]));
                unsigned int b2 = __builtin_bit_cast(unsigned int, exp2_raw(sc[e][c][2]));
                unsigned int b3 = __builtin_bit_cast(unsigned int, exp2_raw(sc[e][c][3]));
                uint2 u;
                u.x = (b0 >> 16) | (b1 & 0xffff0000u);
                u.y = (b2 >> 16) | (b3 & 0xffff0000u);
                int pb = ((c * 2 + (quad >> 1)) + (l16 >> 1)) & 7;
                *(uint2*)&Ps[wave][e * 16 + l16][pb * 8 + (quad & 1) * 4] = u;
            }

        // O += P V ; l += P 1   (read rotation matches: l16>>1)
        __builtin_amdgcn_s_setprio(1);
        for (int ks = 0; ks < 2; ks++) {
            int blkr = (ks * 4 + quad + (l16 >> 1)) & 7;
            bf16x8 pf0 = *(const bf16x8*)&Ps[wave][l16][blkr * 8];
            bf16x8 pf1 = *(const bf16x8*)&Ps[wave][16 + l16][blkr * 8];
            lacc[0] = __builtin_amdgcn_mfma_f32_16x16x32_bf16(pf0, ones, lacc[0], 0, 0, 0);
            lacc[1] = __builtin_amdgcn_mfma_f32_16x16x32_bf16(pf1, ones, lacc[1], 0, 0, 0);
            for (int cv = 0; cv < 4; cv++) {
                bf16x8 vf = *(const bf16x8*)&Vs[cv * 16 + l16]
                                               [((ks * 4 + quad) ^ (l16 & 7)) * 8];
                oacc[0][cv] = __builtin_amdgcn_mfma_f32_16x16x32_bf16(pf0, vf, oacc[0][cv], 0, 0, 0);
                oacc[1][cv] = __builtin_amdgcn_mfma_f32_16x16x32_bf16(pf1, vf, oacc[1][cv], 0, 0, 0);
            }
        }
        __builtin_amdgcn_s_setprio(0);
        __syncthreads();
    }

    if (split) {
        size_t p = ((size_t)((b * 16 + h) * 16 + qt)) * 2 + half;
        float* Op = Opart + p * 8192;
        for (int e = 0; e < 2; e++)
            for (int cv = 0; cv < 4; cv++)
                for (int r = 0; r < 4; r++)
                    Op[(e * 64 + wave * 16 + quad * 4 + r) * 64 + cv * 16 + l16] =
                        oacc[e][cv][r];
        if (l16 == 0)
            for (int e = 0; e < 2; e++)
                for (int r = 0; r < 4; r++)
                    Lpart[p * 128 + e * 64 + wave * 16 + quad * 4 + r] = lacc[e][r];
    } else {
        for (int e = 0; e < 2; e++) {
            float invl[4];
            for (int r = 0; r < 4; r++) invl[r] = 1.0f / lacc[e][r];
            for (int cv = 0; cv < 4; cv++)
                for (int r = 0; r < 4; r++) {
                    int qrow = q0 + e * 64 + 16 * wave + quad * 4 + r;
                    int d = h * 64 + cv * 16 + l16;
                    Y[((size_t)b * 2048 + qrow) * 1024 + d] =
                        f2bf(oacc[e][cv][r] * invl[r]);
                }
        }
    }
}

// -------------------------------------------- combine split-K partials -> Y
__global__ void attn_combine(const float* __restrict__ Opart,
                             const float* __restrict__ Lpart,
                             unsigned short* __restrict__ Y) {
    int blk = blockIdx.x;                    // (b*16+h)*16+qt, 512 blocks
    int qt = blk & 15, h = (blk >> 4) & 15, b = blk >> 8;
    const float* O0 = Opart + (size_t)blk * 2 * 8192;
    const float* O1 = O0 + 8192;
    const float* L0 = Lpart + (size_t)blk * 2 * 128;
    const float* L1 = L0 + 128;
    int t = threadIdx.x;
    for (int i = 0; i < 8; i++) {
        int idx4 = i * 256 + t;              // float4 index (2048 total)
        int q = idx4 >> 4;
        int dk = (idx4 & 15) * 4;
        float4 a = *(const float4*)&O0[idx4 * 4];
        float4 c = *(const float4*)&O1[idx4 * 4];
        float inv = 1.0f / (L0[q] + L1[q]);
        uint2 u;
        u.x = (unsigned)f2bf((a.x + c.x) * inv) |
              ((unsigned)f2bf((a.y + c.y) * inv) << 16);
        u.y = (unsigned)f2bf((a.z + c.z) * inv) |
              ((unsigned)f2bf((a.w + c.w) * inv) << 16);
        int qrow = qt * 128 + q;
        *(uint2*)&Y[((size_t)b * 2048 + qrow) * 1024 + h * 64 + dk] = u;
    }
}

// ---------------------------------------------------------------- launcher
extern "C" void kernel_launch(void* const* d_in, const int* in_sizes, int n_in,
                              void* d_out, int out_size, void* d_ws, size_t ws_size,
                              hipStream_t stream) {
    const float* x     = (const float*)d_in[0];
    const float* alpha = (const float*)d_in[1];
    const float* bias  = (const float*)d_in[2];
    const float* Wq    = (const float*)d_in[3];
    const float* bq    = (const float*)d_in[4];
    const float* Wk    = (const float*)d_in[5];
    const float* bk    = (const float*)d_in[6];
    const float* Wv    = (const float*)d_in[7];
    const float* bv    = (const float*)d_in[8];
    const float* Wo    = (const float*)d_in[9];
    const float* bo    = (const float*)d_in[10];
    float* out = (float*)d_out;

    char* ws = (char*)d_ws;
    const size_t MB = 1048576;
    unsigned short* xb    = (unsigned short*)(ws);            // [0,8M), Yb later
    unsigned short* wqt   = (unsigned short*)(ws + 8 * MB);
    unsigned short* wkt   = (unsigned short*)(ws + 10 * MB);
    unsigned short* wvt   = (unsigned short*)(ws + 12 * MB);
    unsigned short* wot   = (unsigned short*)(ws + 14 * MB);
    unsigned short* Qb    = (unsigned short*)(ws + 16 * MB);
    unsigned short* Kb    = (unsigned short*)(ws + 24 * MB);
    unsigned short* Vtb   = (unsigned short*)(ws + 32 * MB);
    unsigned short* biasP = (unsigned short*)(ws + 40 * MB);  // 16 MB
    float*          Opart = (float*)(ws + 56 * MB);           // 32 MB
    float*          Lpart = (float*)(ws + 88 * MB);           // 0.5 MB
    unsigned short* Yb    = xb;
    int split = (ws_size >= 90 * MB) ? 1 : 0;

    prep<<<6144, 256, 0, stream>>>(x, xb, Wq, Wk, Wv, Wo, wqt, wkt, wvt, wot);

    // GEMM blocks (y<24) + bias-permute blocks (y>=24, overlapped)
    gemm_qkv<<<dim3(32, 56), 256, 0, stream>>>(
        xb, wqt, wkt, wvt, bq, bk, bv, alpha, bias, biasP, Qb, Kb, Vtb);

    if (split) {
        attn_kernel<<<dim3(16, 16, 4), 256, 0, stream>>>(
            Qb, Kb, Vtb, biasP, Yb, Opart, Lpart, 1);
        attn_combine<<<512, 256, 0, stream>>>(Opart, Lpart, Yb);
    } else {
        attn_kernel<<<dim3(16, 16, 2), 256, 0, stream>>>(
            Qb, Kb, Vtb, biasP, Yb, Opart, Lpart, 0);
    }

    gemm_out<<<dim3(32, 16), 256, 0, stream>>>(Yb, wot, bo, out);
}